// Round 23
// baseline (232.085 us; speedup 1.0000x reference)
//
#include <hip/hip_runtime.h>
#include <math.h>

#define CH 64
#define S 64
#define S2 (64 * 64)
#define S3 (64 * 64 * 64)

typedef short short8_t __attribute__((ext_vector_type(8)));
typedef float float4_t __attribute__((ext_vector_type(4)));

typedef __attribute__((address_space(3))) float lds_f;
typedef __attribute__((address_space(1))) const float gbl_f;

__device__ __align__(16) unsigned short WB_buf[CH * CH];  // bf16 W[o][c]

__device__ __forceinline__ unsigned short f2bf(float f) {  // RNE to bf16
  unsigned int u = __float_as_uint(f);
  return (unsigned short)((u + 0x7FFFu + ((u >> 16) & 1u)) >> 16);
}

__device__ __forceinline__ void dma4(const float* g, void* l) {
  __builtin_amdgcn_global_load_lds((gbl_f*)g, (lds_f*)l, 4, 0, 0);
}

#define WAITV(N) __asm__ __volatile__("s_waitcnt vmcnt(" #N ")" ::: "memory")

// ---------------------------------------------------------------------------
// Kernel 0: W -> bf16 row-major (16B-aligned rows for MFMA A-frags).
// ---------------------------------------------------------------------------
__global__ __launch_bounds__(256) void wprep(const float* __restrict__ W) {
  int i = blockIdx.x * 256 + threadIdx.x;  // 4096
  WB_buf[i] = f2bf(W[i]);
}

// ---------------------------------------------------------------------------
// Fused kernel, LDS-DMA pipelined (T3/T4 per-wave, barrier-free):
// Phase A: 10 rows/channel (q + 9 K taps) DMA'd via global_load_lds into a
//   3-slot ring, depth-2 prefetch, s_waitcnt vmcnt(20) + sched_barrier(0)
//   before consuming (all loop VMEM is ours -> exact counts). Registers
//   never hold in-flight data -> prefetch depth costs 0 VGPRs.
// pe: VALU + SGPR loads (uniform) -> frees the Q-panel so LDS fits 3 blk/CU.
// Phase B: 9 V rows/channel, 2-slot ring, depth-1, vmcnt(9); x -> bf16 panel
//   (own-slot writes, program-ordered). Phase P: MFMA projection (r19-21).
// Per-wave LDS region 13312 B: A-ring 3x2560 | B-ring 2x2304 + panel@4608
// (A-ring overlaps panel in space, disjoint in time; vmcnt(0) after A
// guards late redundant DMAs). Block total 53248 B -> 3 blocks/CU.
// ---------------------------------------------------------------------------
__global__ __launch_bounds__(256) void attn_fused(const float* __restrict__ Q,
                                                  const float* __restrict__ K,
                                                  const float* __restrict__ V,
                                                  const float* __restrict__ pe,
                                                  const float* __restrict__ bias,
                                                  float* __restrict__ out) {
  __shared__ __align__(16) char region[4][13312];  // 53248 B
  int tid = threadIdx.x;
  int lane = tid & 63;
  int wv = tid >> 6;
  char* rgn = region[wv];

  // XCD-aware bijective swizzle (2048 % 8 == 0)
  int raw = blockIdx.x;
  int sw = (raw & 7) * 256 + (raw >> 3);
  int b = sw >> 10;
  int r = sw & 1023;
  int d = r >> 4;                                             // 0..63
  int hu = __builtin_amdgcn_readfirstlane((r & 15) * 4 + wv);  // 0..63, uniform

  size_t bbase = (size_t)b << 24;
  const float* Qb = Q + bbase;
  const float* Kb = K + bbase;
  const float* Vb = V + bbase;
  float* outb = out + bbase;

  float lmL = (lane == 0) ? 0.f : 1.f;
  float lmR = (lane == 63) ? 0.f : 1.f;

  // uniform row bases (clamped) + OOB masks
  int rowoff[9];
  float okf[9];
  const float* krow[9];
#pragma unroll
  for (int dz = 0; dz < 3; ++dz)
#pragma unroll
    for (int dy = 0; dy < 3; ++dy) {
      int rr = dz * 3 + dy;
      int zz = d + dz - 1, yy = hu + dy - 1;
      bool ok = ((unsigned)zz < 64u) & ((unsigned)yy < 64u);
      int zc = zz < 0 ? 0 : (zz > 63 ? 63 : zz);
      int yc = yy < 0 ? 0 : (yy > 63 ? 63 : yy);
      rowoff[rr] = __builtin_amdgcn_readfirstlane(zc * S2 + yc * S);
      krow[rr] = Kb + rowoff[rr];
      okf[rr] = ok ? 1.f : 0.f;
    }
  int upos = d * S2 + hu * S;
  int pos = upos + lane;

  float spe[27];
  float sC[9], sXR[9], sXL[9];
#pragma unroll
  for (int t = 0; t < 27; ++t) spe[t] = 0.f;
#pragma unroll
  for (int rr = 0; rr < 9; ++rr) { sC[rr] = 0.f; sXR[rr] = 0.f; sXL[rr] = 0.f; }

  // ---- Phase A with depth-2 LDS-DMA pipeline ----
  // prologue: issue batches for c=0 (slot 0) and c=1 (slot 1)
#pragma unroll
  for (int p0 = 0; p0 < 2; ++p0) {
    char* sb = rgn + p0 * 2560;
    int coff = p0 * S3;
    dma4(Qb + coff + pos, sb);
#pragma unroll
    for (int rr = 0; rr < 9; ++rr)
      dma4(krow[rr] + coff + lane, sb + (1 + rr) * 256);
  }
  int sCons = 0, sIss = 2;
#pragma unroll 1
  for (int c = 0; c < CH; ++c) {
    int cn = c + 2; cn = cn > 63 ? 63 : cn;
    {  // issue batch cn into slot sIss
      char* sb = rgn + sIss * 2560;
      int coff = cn * S3;
      dma4(Qb + coff + pos, sb);
#pragma unroll
      for (int rr = 0; rr < 9; ++rr)
        dma4(krow[rr] + coff + lane, sb + (1 + rr) * 256);
    }
    WAITV(20);  // batches c+1, c+2 outstanding (10 each) -> batch c complete
    __builtin_amdgcn_sched_barrier(0);
    const float* kb = (const float*)(rgn + sCons * 2560);
    float q = kb[lane];
    float rv[9];
#pragma unroll
    for (int rr = 0; rr < 9; ++rr) rv[rr] = kb[64 + rr * 64 + lane];
    float qR = __shfl_down(q, 1);
    float qL = __shfl_up(q, 1);
#pragma unroll
    for (int rr = 0; rr < 9; ++rr) {
      sC[rr]  = fmaf(q,  rv[rr], sC[rr]);
      sXR[rr] = fmaf(qR, rv[rr], sXR[rr]);  // lane+1's left tap
      sXL[rr] = fmaf(qL, rv[rr], sXL[rr]);  // lane-1's right tap
    }
    const float* pec = pe + c * 27;  // uniform -> scalar loads
#pragma unroll
    for (int t = 0; t < 27; ++t) spe[t] = fmaf(q, pec[t], spe[t]);
    sCons = (sCons == 2) ? 0 : sCons + 1;
    sIss  = (sIss == 2) ? 0 : sIss + 1;
  }
  WAITV(0);  // drain redundant tail DMAs before the panel region is reused

  // ---- assemble 27 tap scores (18 shuffles) ----
  float s[27];
#pragma unroll
  for (int rr = 0; rr < 9; ++rr) {
    float lt = __shfl_up(sXR[rr], 1);
    float rt = __shfl_down(sXL[rr], 1);
    s[rr * 3]     = fmaf(lt * lmL, okf[rr], spe[rr * 3]);
    s[rr * 3 + 1] = fmaf(sC[rr],   okf[rr], spe[rr * 3 + 1]);
    s[rr * 3 + 2] = fmaf(rt * lmR, okf[rr], spe[rr * 3 + 2]);
  }

  // ---- softmax (base-2; normalization folded into weights) ----
  const float SC = 0.125f * 1.44269504088896f;
#pragma unroll
  for (int t = 0; t < 27; ++t) s[t] *= SC;
  float m = s[0];
#pragma unroll
  for (int t = 1; t < 27; ++t) m = fmaxf(m, s[t]);
  float sum = 0.f;
#pragma unroll
  for (int t = 0; t < 27; ++t) {
    s[t] = exp2f(s[t] - m);
    sum += s[t];
  }
  float inv = 1.f / sum;

  // ---- weights + V row pointers ----
  float wC[9], sLs[9], sRs[9];
  const float* vrow[9];
#pragma unroll
  for (int rr = 0; rr < 9; ++rr) {
    vrow[rr] = Vb + rowoff[rr];
    float f = inv * okf[rr];
    float wL = s[rr * 3] * f;
    wC[rr]   = s[rr * 3 + 1] * f;
    float wR = s[rr * 3 + 2] * f;
    sLs[rr] = __shfl_down(wL, 1);
    sRs[rr] = __shfl_up(wR, 1);
  }

  __asm__ __volatile__("" ::: "memory");
  __threadfence_block();

  // ---- Phase B: depth-1 LDS-DMA pipeline; x -> bf16 panel (own slot) ----
  unsigned short* xpan = (unsigned short*)(rgn + 4608);  // [64][68] bf16
  {  // prologue: batch 0 into slot 0
    char* sb = rgn;
#pragma unroll
    for (int rr = 0; rr < 9; ++rr) dma4(vrow[rr] + lane, sb + rr * 256);
  }
#pragma unroll 1
  for (int c = 0; c < CH; ++c) {
    int cn = c + 1; cn = cn > 63 ? 63 : cn;
    {  // issue batch cn into slot (c+1)&1
      char* sb = rgn + ((c + 1) & 1) * 2304;
      int coff = cn * S3;
#pragma unroll
      for (int rr = 0; rr < 9; ++rr)
        dma4(vrow[rr] + coff + lane, sb + rr * 256);
    }
    WAITV(9);  // only batch c+1 outstanding -> batch c complete
    __builtin_amdgcn_sched_barrier(0);
    const float* vb2 = (const float*)(rgn + (c & 1) * 2304);
    float rv[9];
#pragma unroll
    for (int rr = 0; rr < 9; ++rr) rv[rr] = vb2[rr * 64 + lane];
    float own = 0.f, cR = 0.f, cL = 0.f;
#pragma unroll
    for (int rr = 0; rr < 9; ++rr) {
      own = fmaf(wC[rr],  rv[rr], own);
      cR  = fmaf(sLs[rr], rv[rr], cR);
      cL  = fmaf(sRs[rr], rv[rr], cL);
    }
    float x_c = own + __shfl_up(cR, 1) * lmL + __shfl_down(cL, 1) * lmR;
    xpan[lane * 68 + c] = f2bf(x_c);  // own slot, program-ordered
  }

  __asm__ __volatile__("" ::: "memory");
  __threadfence_block();

  // ---- Phase P: MFMA projection out = W x + bias (r19-21 layouts) ----
  {
    int n16 = lane & 15, g = lane >> 4;
#pragma unroll 1
    for (int ot = 0; ot < 4; ++ot) {
      short8_t a0 = *(const short8_t*)(WB_buf + (ot * 16 + n16) * CH + g * 8);
      short8_t a1 = *(const short8_t*)(WB_buf + (ot * 16 + n16) * CH + 32 + g * 8);
      int obase = ot * 16 + 4 * g;
      float4_t bv = *(const float4_t*)(bias + obase);
#pragma unroll 1
      for (int pt = 0; pt < 4; ++pt) {
        const unsigned short* bp = &xpan[(pt * 16 + n16) * 68 + g * 8];
        union { short8_t v; uint2 h[2]; } u0, u1;
        u0.h[0] = *(const uint2*)(bp);
        u0.h[1] = *(const uint2*)(bp + 4);
        u1.h[0] = *(const uint2*)(bp + 32);
        u1.h[1] = *(const uint2*)(bp + 36);
        float4_t acc = {0.f, 0.f, 0.f, 0.f};
        acc = __builtin_amdgcn_mfma_f32_16x16x32_bf16(a0, u0.v, acc, 0, 0, 0);
        acc = __builtin_amdgcn_mfma_f32_16x16x32_bf16(a1, u1.v, acc, 0, 0, 0);
#pragma unroll
        for (int j = 0; j < 4; ++j)
          outb[(obase + j) * S3 + upos + pt * 16 + n16] = acc[j] + bv[j];
      }
    }
  }
}

// ---------------------------------------------------------------------------
extern "C" void kernel_launch(void* const* d_in, const int* in_sizes, int n_in,
                              void* d_out, int out_size, void* d_ws, size_t ws_size,
                              hipStream_t stream) {
  const float* Q = (const float*)d_in[0];
  const float* K = (const float*)d_in[1];
  const float* V = (const float*)d_in[2];
  const float* pe = (const float*)d_in[3];
  const float* W = (const float*)d_in[4];
  const float* bias = (const float*)d_in[5];
  float* out = (float*)d_out;

  wprep<<<16, 256, 0, stream>>>(W);
  attn_fused<<<2048, 256, 0, stream>>>(Q, K, V, pe, bias, out);
}

// Round 24
// 203.782 us; speedup vs baseline: 1.1389x; 1.1389x over previous
//
#include <hip/hip_runtime.h>
#include <math.h>

#define CH 64
#define S 64
#define S2 (64 * 64)
#define S3 (64 * 64 * 64)

typedef short short8_t __attribute__((ext_vector_type(8)));
typedef float float4_t __attribute__((ext_vector_type(4)));

__device__ __align__(16) unsigned short WB_buf[CH * CH];   // bf16 W[o][c]
__device__ __align__(16) unsigned short peT_buf[32 * 64];  // bf16 peT[t][c], t>=27 zero

__device__ __forceinline__ unsigned short f2bf(float f) {  // RNE to bf16
  unsigned int u = __float_as_uint(f);
  return (unsigned short)((u + 0x7FFFu + ((u >> 16) & 1u)) >> 16);
}

// ---------------------------------------------------------------------------
// Kernel 0: W -> bf16 row-major; pe -> bf16 transposed [t][c] padded to 32 t.
// ---------------------------------------------------------------------------
__global__ __launch_bounds__(256) void wprep(const float* __restrict__ W,
                                             const float* __restrict__ pe) {
  int i = blockIdx.x * 256 + threadIdx.x;  // 0..6143
  if (i < 4096) {
    WB_buf[i] = f2bf(W[i]);
  } else {
    int j = i - 4096;  // 0..2047
    int t = j >> 6, c = j & 63;
    peT_buf[t * 64 + c] = (t < 27) ? f2bf(pe[c * 27 + t]) : (unsigned short)0;
  }
}

// ---------------------------------------------------------------------------
// Fused kernel — measured optimum (r21, 203.07 us total). Structure:
// Phase A: QK tap scores (27 accs) + Q->bf16 pack into per-wave LDS panel.
// pe-MFMA: spe = peT x Q (16 mfma), C-frags redistributed via LDS float view.
// assemble -> softmax -> weights -> Phase B: V-gather -> x bf16 panel.
// Phase P: out = W x (32 mfma, ot-outer/pt-inner minimal live frags) + bias.
// Plain launch bounds (min-waves hints spill: r2-r13). Barrier-free: panels
// are per-wave; same-wave DS is HW-in-order; compiler fenced at handoffs.
// Latency-bound at ~2.5 waves/SIMD (unified-regfile cap ~150 regs);
// occupancy/MLP/DMA-pipeline levers all A/B-nulled or regressed (r16-r23).
// ---------------------------------------------------------------------------
__global__ __launch_bounds__(256) void attn_fused(const float* __restrict__ Q,
                                                  const float* __restrict__ K,
                                                  const float* __restrict__ V,
                                                  const float* __restrict__ bias,
                                                  float* __restrict__ out) {
  __shared__ unsigned short xs[4][CH][68];  // 34816 B (time-shared: Q/spe/x)
  int tid = threadIdx.x;
  int lane = tid & 63;
  int wv = tid >> 6;

  // XCD-aware bijective swizzle (2048 % 8 == 0)
  int raw = blockIdx.x;
  int sw = (raw & 7) * 256 + (raw >> 3);
  int b = sw >> 10;
  int r = sw & 1023;
  int d = r >> 4;                                             // 0..63
  int hu = __builtin_amdgcn_readfirstlane((r & 15) * 4 + wv);  // 0..63, uniform

  size_t bbase = (size_t)b << 24;
  const float* Qb = Q + bbase;
  const float* Kb = K + bbase;
  const float* Vb = V + bbase;
  float* outb = out + bbase;

  float lmL = (lane == 0) ? 0.f : 1.f;
  float lmR = (lane == 63) ? 0.f : 1.f;

  // uniform row offsets (clamped) + OOB masks; K pointers now, V later
  int rowoff[9];
  float okf[9];
  const float* krow[9];
#pragma unroll
  for (int dz = 0; dz < 3; ++dz)
#pragma unroll
    for (int dy = 0; dy < 3; ++dy) {
      int rr = dz * 3 + dy;
      int zz = d + dz - 1, yy = hu + dy - 1;
      bool ok = ((unsigned)zz < 64u) & ((unsigned)yy < 64u);
      int zc = zz < 0 ? 0 : (zz > 63 ? 63 : zz);
      int yc = yy < 0 ? 0 : (yy > 63 ? 63 : yy);
      rowoff[rr] = __builtin_amdgcn_readfirstlane(zc * S2 + yc * S);
      krow[rr] = Kb + rowoff[rr];
      okf[rr] = ok ? 1.f : 0.f;
    }
  int upos = d * S2 + hu * S;
  int pos = upos + lane;

  float sC[9], sXR[9], sXL[9];
#pragma unroll
  for (int rr = 0; rr < 9; ++rr) { sC[rr] = 0.f; sXR[rr] = 0.f; sXL[rr] = 0.f; }

  // ---- Phase A: QK tap scores + Q->bf16 LDS pack (own row [lane][c]) ----
#pragma unroll 2
  for (int c2 = 0; c2 < CH; c2 += 2) {
    unsigned int qpack = 0;
#pragma unroll
    for (int u = 0; u < 2; ++u) {
      int coff = (c2 + u) * S3;
      float q = Qb[coff + pos];
      float rv[9];
#pragma unroll
      for (int rr = 0; rr < 9; ++rr) rv[rr] = krow[rr][coff + lane];
      float qR = __shfl_down(q, 1);
      float qL = __shfl_up(q, 1);
#pragma unroll
      for (int rr = 0; rr < 9; ++rr) {
        sC[rr]  = fmaf(q,  rv[rr], sC[rr]);
        sXR[rr] = fmaf(qR, rv[rr], sXR[rr]);  // lane+1's left tap
        sXL[rr] = fmaf(qL, rv[rr], sXL[rr]);  // lane-1's right tap
      }
      qpack |= ((unsigned int)f2bf(q)) << (16 * u);
    }
    *(unsigned int*)&xs[wv][lane][c2] = qpack;  // own slot, program-ordered
  }

  __asm__ __volatile__("" ::: "memory");
  __threadfence_block();

  // ---- pe-MFMA: spe[t][p] = peT[t][c] * Qbf[c][p] -> LDS float[64][33] ----
  {
    int n16 = lane & 15, g = lane >> 4;
    short8_t pfr[4];  // [mt][kc]
#pragma unroll
    for (int mt = 0; mt < 2; ++mt)
#pragma unroll
      for (int kc = 0; kc < 2; ++kc)
        pfr[mt * 2 + kc] =
            *(const short8_t*)(peT_buf + (mt * 16 + n16) * 64 + kc * 32 + g * 8);
    float* spf = (float*)&xs[wv][0][0];  // view: float[64][33] ([p][t])
#pragma unroll 1
    for (int nt = 0; nt < 4; ++nt) {
      const unsigned short* bp = &xs[wv][nt * 16 + n16][g * 8];
      union { short8_t v; uint2 h[2]; } u0, u1;
      u0.h[0] = *(const uint2*)(bp);
      u0.h[1] = *(const uint2*)(bp + 4);
      u1.h[0] = *(const uint2*)(bp + 32);
      u1.h[1] = *(const uint2*)(bp + 36);
#pragma unroll
      for (int mt = 0; mt < 2; ++mt) {
        float4_t acc = {0.f, 0.f, 0.f, 0.f};
        acc = __builtin_amdgcn_mfma_f32_16x16x32_bf16(pfr[mt * 2],     u0.v, acc, 0, 0, 0);
        acc = __builtin_amdgcn_mfma_f32_16x16x32_bf16(pfr[mt * 2 + 1], u1.v, acc, 0, 0, 0);
        // D: col(p)=n16, row(t)=mt*16+g*4+j -> write [p][t] rows this nt owns
#pragma unroll
        for (int j = 0; j < 4; ++j)
          spf[(nt * 16 + n16) * 33 + mt * 16 + g * 4 + j] = acc[j];
      }
    }
  }

  __asm__ __volatile__("" ::: "memory");
  __threadfence_block();

  // ---- assemble 27 tap scores; pe part read straight from LDS ----
  float s[27];
  {
    const float* spf = (const float*)&xs[wv][0][0];
    int sbase = lane * 33;
#pragma unroll
    for (int rr = 0; rr < 9; ++rr) {
      float lt = __shfl_up(sXR[rr], 1);
      float rt = __shfl_down(sXL[rr], 1);
      s[rr * 3]     = fmaf(lt * lmL, okf[rr], spf[sbase + rr * 3]);
      s[rr * 3 + 1] = fmaf(sC[rr],   okf[rr], spf[sbase + rr * 3 + 1]);
      s[rr * 3 + 2] = fmaf(rt * lmR, okf[rr], spf[sbase + rr * 3 + 2]);
    }
  }

  // ---- softmax (base-2; normalization folded into weights) ----
  const float SC = 0.125f * 1.44269504088896f;
#pragma unroll
  for (int t = 0; t < 27; ++t) s[t] *= SC;
  float m = s[0];
#pragma unroll
  for (int t = 1; t < 27; ++t) m = fmaxf(m, s[t]);
  float sum = 0.f;
#pragma unroll
  for (int t = 0; t < 27; ++t) {
    s[t] = exp2f(s[t] - m);
    sum += s[t];
  }
  float inv = 1.f / sum;

  // ---- weights + V row pointers (deferred live range) ----
  float wC[9], sLs[9], sRs[9];
  const float* vrow[9];
#pragma unroll
  for (int rr = 0; rr < 9; ++rr) {
    vrow[rr] = Vb + rowoff[rr];
    float f = inv * okf[rr];
    float wL = s[rr * 3] * f;
    wC[rr]   = s[rr * 3 + 1] * f;
    float wR = s[rr * 3 + 2] * f;
    sLs[rr] = __shfl_down(wL, 1);
    sRs[rr] = __shfl_up(wR, 1);
  }

  __asm__ __volatile__("" ::: "memory");
  __threadfence_block();

  // ---- Phase B: V-gather -> x bf16 pairs -> own LDS row [lane][c] ----
#pragma unroll 2
  for (int c2 = 0; c2 < CH; c2 += 2) {
    unsigned int packed = 0;
#pragma unroll
    for (int u = 0; u < 2; ++u) {
      int coff = (c2 + u) * S3;
      float rv[9];
#pragma unroll
      for (int rr = 0; rr < 9; ++rr) rv[rr] = vrow[rr][coff + lane];
      float own = 0.f, cR = 0.f, cL = 0.f;
#pragma unroll
      for (int rr = 0; rr < 9; ++rr) {
        own = fmaf(wC[rr], rv[rr], own);
        cR  = fmaf(sLs[rr], rv[rr], cR);
        cL  = fmaf(sRs[rr], rv[rr], cL);
      }
      float x_c = own + __shfl_up(cR, 1) * lmL + __shfl_down(cL, 1) * lmR;
      packed |= ((unsigned int)f2bf(x_c)) << (16 * u);
    }
    *(unsigned int*)&xs[wv][lane][c2] = packed;
  }

  __asm__ __volatile__("" ::: "memory");
  __threadfence_block();

  // ---- Phase P: MFMA projection, ot-outer/pt-inner, minimal live frags ----
  {
    int n16 = lane & 15, g = lane >> 4;
#pragma unroll 1
    for (int ot = 0; ot < 4; ++ot) {
      short8_t a0 = *(const short8_t*)(WB_buf + (ot * 16 + n16) * CH + g * 8);
      short8_t a1 = *(const short8_t*)(WB_buf + (ot * 16 + n16) * CH + 32 + g * 8);
      int obase = ot * 16 + 4 * g;
      float4_t bv = *(const float4_t*)(bias + obase);
#pragma unroll 1
      for (int pt = 0; pt < 4; ++pt) {
        const unsigned short* bp = &xs[wv][pt * 16 + n16][g * 8];
        union { short8_t v; uint2 h[2]; } u0, u1;
        u0.h[0] = *(const uint2*)(bp);
        u0.h[1] = *(const uint2*)(bp + 4);
        u1.h[0] = *(const uint2*)(bp + 32);
        u1.h[1] = *(const uint2*)(bp + 36);
        float4_t acc = {0.f, 0.f, 0.f, 0.f};
        acc = __builtin_amdgcn_mfma_f32_16x16x32_bf16(a0, u0.v, acc, 0, 0, 0);
        acc = __builtin_amdgcn_mfma_f32_16x16x32_bf16(a1, u1.v, acc, 0, 0, 0);
#pragma unroll
        for (int j = 0; j < 4; ++j)
          outb[(obase + j) * S3 + upos + pt * 16 + n16] = acc[j] + bv[j];
      }
    }
  }
}

// ---------------------------------------------------------------------------
extern "C" void kernel_launch(void* const* d_in, const int* in_sizes, int n_in,
                              void* d_out, int out_size, void* d_ws, size_t ws_size,
                              hipStream_t stream) {
  const float* Q = (const float*)d_in[0];
  const float* K = (const float*)d_in[1];
  const float* V = (const float*)d_in[2];
  const float* pe = (const float*)d_in[3];
  const float* W = (const float*)d_in[4];
  const float* bias = (const float*)d_in[5];
  float* out = (float*)d_out;

  wprep<<<24, 256, 0, stream>>>(W, pe);
  attn_fused<<<2048, 256, 0, stream>>>(Q, K, V, bias, out);
}